// Round 5
// baseline (533.526 us; speedup 1.0000x reference)
//
#include <hip/hip_runtime.h>

// HyenaFilter = implicit-filter MLP (tiny) + FFT convolution.
// fftconv (fft_size=16384 >= 2L) == causal linear conv; bias folded into k[0].
// R4/R5: overlap-add with F=8192 FFTs, 8 pts/thread (16 VGPRs data) so the
//     whole kernel fits the 64-VGPR budget the compiler insists on
//     (R1-R3: 64 data regs live -> ~650MB scratch spill, knobs no-op'd).
//     y[0:4096)   = inv(K0*Z0)[0:4096)
//     y[4096:8192)= inv(K0*Z0)[4096:) + inv(K0*Z1 + K1*Z0)[0:4096)
//     K0 parked in LDS (thread-private slots), K1/C in regs.
//     (R5 = R4 resubmitted: container died before measuring R4.)

#define DIMC  768
#define BANDS 16
#define FO    64
#define LSEQ  8192
#define F8    8192
#define PI_F  3.14159265358979323846f

// bank-decorrelating swizzle for float2 indices (fixes stride-16/8 patterns)
__device__ __forceinline__ int swz(int i) { return i ^ ((i >> 4) & 15); }

// ---------- FFT building blocks (N=8192, 1024 threads, 8 pts/thread) ------
// Ownerships (pos of reg j for thread t):
//   A: j*1024 + t                      (bits 12:10 = j)
//   B: (t>>7)*1024 + j*128 + (t&127)   (bits  9:7 = j)
//   C: (t>>4)*128  + j*16  + (t&15)    (bits  6:4 = j)
//   D: (t>>1)*16   + j*2   + (t&1)     (bits  3:1 = j)
//   E: t*8 + j                         (bit     0 = j0)

template<int SHIFT, int SMAX, int SMIN>
__device__ __forceinline__ void fwd_stages8(float2 (&r)[8], int base)
{
#pragma unroll
    for (int S = SMAX; S >= SMIN; S >>= 1) {
        const int s = S << SHIFT;
        const float scale = -PI_F / (float)s;
#pragma unroll
        for (int g = 0; g < 4; ++g) {
            const int j  = ((g & ~(S - 1)) << 1) | (g & (S - 1));
            const int jS = j + S;
            int wexp = (base + (j << SHIFT)) & (s - 1);
            float ang = scale * (float)wexp;
            float sn, cs;
            __sincosf(ang, &sn, &cs);
            float2 u = r[j], v = r[jS];
            r[j].x = u.x + v.x;
            r[j].y = u.y + v.y;
            float dx = u.x - v.x;
            float dy = u.y - v.y;
            r[jS].x = dx * cs - dy * sn;
            r[jS].y = dx * sn + dy * cs;
        }
    }
}

template<int SHIFT, int SMIN, int SMAX>
__device__ __forceinline__ void inv_stages8(float2 (&r)[8], int base)
{
#pragma unroll
    for (int S = SMIN; S <= SMAX; S <<= 1) {
        const int s = S << SHIFT;
        const float scale = PI_F / (float)s;   // conj twiddle
#pragma unroll
        for (int g = 0; g < 4; ++g) {
            const int j  = ((g & ~(S - 1)) << 1) | (g & (S - 1));
            const int jS = j + S;
            int wexp = (base + (j << SHIFT)) & (s - 1);
            float ang = scale * (float)wexp;
            float sn, cs;
            __sincosf(ang, &sn, &cs);
            float2 u = r[j], v = r[jS];
            float vx = v.x * cs - v.y * sn;
            float vy = v.x * sn + v.y * cs;
            r[j].x  = u.x + vx;
            r[j].y  = u.y + vy;
            r[jS].x = u.x - vx;
            r[jS].y = u.y - vy;
        }
    }
}

__device__ __forceinline__ void xchg8(float2 (&r)[8], float2* xb,
                                      int baseW, int shiftW, int baseR, int shiftR)
{
    __syncthreads();   // WAR vs previous reads of xb
#pragma unroll
    for (int j = 0; j < 8; ++j) xb[swz(baseW + (j << shiftW))] = r[j];
    __syncthreads();
#pragma unroll
    for (int j = 0; j < 8; ++j) r[j] = xb[swz(baseR + (j << shiftR))];
}

// Forward DIF FFT of 8192, input zero-padded: r[0..3] valid, upper half 0.
// Output scrambled, E-ownership.
__device__ __forceinline__ void fft_fwd8(float2 (&r)[8], float2* xb, int t)
{
    const int bA = t;
    const int bB = ((t >> 7) << 10) | (t & 127);
    const int bC = ((t >> 4) << 7)  | (t & 15);
    const int bD = ((t >> 1) << 4)  | (t & 1);
    const int bE = t << 3;
    // stage s=4096 with v=0: lo = u, hi = u * w  (pos = j*1024+t < 4096)
    const float sc0 = -PI_F / 4096.0f;
#pragma unroll
    for (int j = 0; j < 4; ++j) {
        float ang = sc0 * (float)(bA + (j << 10));
        float sn, cs;
        __sincosf(ang, &sn, &cs);
        float2 u = r[j];
        r[j + 4].x = u.x * cs - u.y * sn;
        r[j + 4].y = u.x * sn + u.y * cs;
    }
    fwd_stages8<10, 2, 1>(r, bA);   // s = 2048, 1024
    xchg8(r, xb, bA, 10, bB, 7);
    fwd_stages8<7, 4, 1>(r, bB);    // s = 512, 256, 128
    xchg8(r, xb, bB, 7, bC, 4);
    fwd_stages8<4, 4, 1>(r, bC);    // s = 64, 32, 16
    xchg8(r, xb, bC, 4, bD, 1);
    fwd_stages8<1, 4, 1>(r, bD);    // s = 8, 4, 2
    xchg8(r, xb, bD, 1, bE, 0);
    // s = 1: twiddle = 1
#pragma unroll
    for (int g = 0; g < 4; ++g) {
        const int j = g << 1;
        float2 u = r[j], v = r[j + 1];
        r[j].x = u.x + v.x;   r[j].y = u.y + v.y;
        r[j + 1].x = u.x - v.x; r[j + 1].y = u.y - v.y;
    }
}

// Inverse DIT FFT of 8192: scrambled E-ownership in -> natural A-ownership out.
__device__ __forceinline__ void fft_inv8(float2 (&r)[8], float2* xb, int t)
{
    const int bA = t;
    const int bB = ((t >> 7) << 10) | (t & 127);
    const int bC = ((t >> 4) << 7)  | (t & 15);
    const int bD = ((t >> 1) << 4)  | (t & 1);
    const int bE = t << 3;
    // s = 1: conj twiddle = 1
#pragma unroll
    for (int g = 0; g < 4; ++g) {
        const int j = g << 1;
        float2 u = r[j], v = r[j + 1];
        r[j].x = u.x + v.x;   r[j].y = u.y + v.y;
        r[j + 1].x = u.x - v.x; r[j + 1].y = u.y - v.y;
    }
    xchg8(r, xb, bE, 0, bD, 1);
    inv_stages8<1, 1, 4>(r, bD);    // s = 2, 4, 8
    xchg8(r, xb, bD, 1, bC, 4);
    inv_stages8<4, 1, 4>(r, bC);    // s = 16, 32, 64
    xchg8(r, xb, bC, 4, bB, 7);
    inv_stages8<7, 1, 4>(r, bB);    // s = 128, 256, 512
    xchg8(r, xb, bB, 7, bA, 10);
    inv_stages8<10, 1, 2>(r, bA);   // s = 1024, 2048
    // final stage s = 4096 (pos = j*1024+t < 4096 for j<4)
    const float scF = PI_F / 4096.0f;
#pragma unroll
    for (int j = 0; j < 4; ++j) {
        float ang = scF * (float)(bA + (j << 10));
        float sn, cs;
        __sincosf(ang, &sn, &cs);
        float2 u = r[j], v = r[j + 4];
        float vx = v.x * cs - v.y * sn;
        float vy = v.x * sn + v.y * cs;
        r[j].x = u.x + vx;     r[j].y = u.y + vy;
        r[j + 4].x = u.x - vx; r[j + 4].y = u.y - vy;
    }
}

// ---------- Kernel 1: MLP hidden states h2[FO][LSEQ] ----------------------
__global__ void hidden_kernel(const float* __restrict__ W0, const float* __restrict__ b0,
                              const float* __restrict__ W1, const float* __restrict__ b1,
                              const float* __restrict__ W2, const float* __restrict__ b2,
                              const float* __restrict__ freq, float* __restrict__ hws)
{
    const int lane = threadIdx.x & 63;
    const int p = blockIdx.x * (blockDim.x >> 6) + (threadIdx.x >> 6);
    if (p >= LSEQ) return;
    const float tt = (float)p / (float)(LSEQ - 1);
    const float w  = 6.283185307179586f * (float)p / (float)LSEQ;

    float acc = b0[lane] + tt * W0[lane];
#pragma unroll
    for (int j = 0; j < BANDS; ++j) {
        float f = 1e-4f + (float)j * ((15.0f - 1e-4f) / 15.0f);
        float a = f * w;
        float sn, cs;
        __sincosf(a, &sn, &cs);
        acc += cs  * W0[(1 + j) * FO + lane];
        acc += -sn * W0[(1 + BANDS + j) * FO + lane];
    }
    float h = __sinf(freq[lane] * acc);

    acc = b1[lane];
#pragma unroll
    for (int e = 0; e < FO; ++e) acc += __shfl(h, e) * W1[e * FO + lane];
    float h1 = __sinf(freq[lane] * acc);

    acc = b2[lane];
#pragma unroll
    for (int e = 0; e < FO; ++e) acc += __shfl(h1, e) * W2[e * FO + lane];
    float h2 = __sinf(freq[lane] * acc);

    hws[lane * LSEQ + p] = h2;    // feature-major, coalesced
}

// ---------- Kernel 2: k[d][p] = (h2 . Wf) * (exp(-t|delta|)+0.05) ---------
#define DCHUNK 96
__global__ __launch_bounds__(256)
void filter_kernel(const float* __restrict__ hws, const float* __restrict__ Wf,
                   float* __restrict__ kws)
{
    const int p  = blockIdx.x * 256 + threadIdx.x;
    const int d0 = blockIdx.y * DCHUNK;
    float h[FO];
#pragma unroll
    for (int j = 0; j < FO; ++j) h[j] = hws[j * LSEQ + p];
    const float tt = (float)p / (float)(LSEQ - 1);
    const float min_decay = -3.0701134573253937f;   // ln(0.01)/1.5
    const float max_decay = -15.350567286626971f;   // ln(0.01)/0.3
    for (int dd = 0; dd < DCHUNK; ++dd) {
        const int d = d0 + dd;
        float acc = 0.f;
#pragma unroll
        for (int j = 0; j < FO; ++j) acc += h[j] * Wf[j * DIMC + d];
        float delta = min_decay + (max_decay - min_decay) * ((float)d / (float)(DIMC - 1));
        float dec = __expf(-tt * fabsf(delta));
        kws[(size_t)d * LSEQ + p] = acc * (dec + 0.05f);
    }
}

// ---------- Kernel 3: overlap-add FFT convolution, one block per channel --
__global__ __launch_bounds__(1024)
void conv_kernel(const float* __restrict__ x, const float* __restrict__ kf,
                 const float* __restrict__ bias, float* __restrict__ out)
{
    __shared__ float2 xb[F8];     // 64 KB exchange buffer
    __shared__ float2 park[F8];   // 64 KB K0-hat park (thread-private slots)
    const int d = blockIdx.x;
    const int t = threadIdx.x;
    const float invn = 1.0f / 8192.0f;
    float2 r[8];

    // --- K0 = FFT(k[0:4096]) / N, parked in LDS ---
    const float* krow = kf + (size_t)d * LSEQ;
#pragma unroll
    for (int j = 0; j < 4; ++j) { r[j].x = krow[(j << 10) + t]; r[j].y = 0.f; }
    if (t == 0) r[0].x += bias[d];   // delta at s=0 == +bias*u term
    fft_fwd8(r, xb, t);
#pragma unroll
    for (int j = 0; j < 8; ++j)
        park[swz((t << 3) + j)] = make_float2(r[j].x * invn, r[j].y * invn);
    // no barrier: each thread re-reads only its own park slots

    // --- K1 = FFT(k[4096:8192]) / N -> creg ---
    float2 creg[8];
#pragma unroll
    for (int j = 0; j < 4; ++j) { r[j].x = krow[4096 + (j << 10) + t]; r[j].y = 0.f; }
    fft_fwd8(r, xb, t);
#pragma unroll
    for (int j = 0; j < 8; ++j) { creg[j].x = r[j].x * invn; creg[j].y = r[j].y * invn; }

    // --- Z0 = FFT(x0[0:4096] + i*x1[0:4096]) ---
    const float* x0 = x + (size_t)d * LSEQ;
    const float* x1 = x + (size_t)(DIMC + d) * LSEQ;
#pragma unroll
    for (int j = 0; j < 4; ++j) { int n = (j << 10) + t; r[j].x = x0[n]; r[j].y = x1[n]; }
    fft_fwd8(r, xb, t);

    // --- A = K0*Z0 (areg); C = K1*Z0 (into creg) ---
    float2 areg[8];
#pragma unroll
    for (int j = 0; j < 8; ++j) {
        float2 z  = r[j];
        float2 k0 = park[swz((t << 3) + j)];
        areg[j].x = k0.x * z.x - k0.y * z.y;
        areg[j].y = k0.x * z.y + k0.y * z.x;
        float2 k1 = creg[j];
        creg[j].x = k1.x * z.x - k1.y * z.y;
        creg[j].y = k1.x * z.y + k1.y * z.x;
    }

    // --- inv(A): y[0:4096) out; keep high half in areg[4..7] ---
    fft_inv8(areg, xb, t);
    float* o0 = out + (size_t)d * LSEQ;
    float* o1 = out + (size_t)(DIMC + d) * LSEQ;
#pragma unroll
    for (int j = 0; j < 4; ++j) {
        int n = (j << 10) + t;
        o0[n] = areg[j].x;
        o1[n] = areg[j].y;
    }

    // --- Z1 = FFT(x[4096:8192] packed) ---
#pragma unroll
    for (int j = 0; j < 4; ++j) { int n = 4096 + (j << 10) + t; r[j].x = x0[n]; r[j].y = x1[n]; }
    fft_fwd8(r, xb, t);

    // --- B = K0*Z1 + C ---
#pragma unroll
    for (int j = 0; j < 8; ++j) {
        float2 z  = r[j];
        float2 k0 = park[swz((t << 3) + j)];
        float bx = k0.x * z.x - k0.y * z.y + creg[j].x;
        float by = k0.x * z.y + k0.y * z.x + creg[j].y;
        r[j].x = bx; r[j].y = by;
    }

    // --- inv(B): y[4096:8192) = invB[0:4096) + Ahi ---
    fft_inv8(r, xb, t);
#pragma unroll
    for (int j = 0; j < 4; ++j) {
        int n = 4096 + (j << 10) + t;
        o0[n] = r[j].x + areg[j + 4].x;
        o1[n] = r[j].y + areg[j + 4].y;
    }
}

extern "C" void kernel_launch(void* const* d_in, const int* in_sizes, int n_in,
                              void* d_out, int out_size, void* d_ws, size_t ws_size,
                              hipStream_t stream)
{
    (void)in_sizes; (void)n_in; (void)out_size; (void)d_ws; (void)ws_size;
    const float* x    = (const float*)d_in[0];
    const float* W0   = (const float*)d_in[1];
    const float* b0   = (const float*)d_in[2];
    const float* W1   = (const float*)d_in[3];
    const float* b1   = (const float*)d_in[4];
    const float* W2   = (const float*)d_in[5];
    const float* b2   = (const float*)d_in[6];
    const float* Wf   = (const float*)d_in[7];
    const float* freq = (const float*)d_in[8];
    const float* bias = (const float*)d_in[9];
    float* out = (float*)d_out;

    // Scratch staged inside d_out (block d only reads its own k row, fully,
    // before writing y into that region):
    float* hws = out;                            // h2[64][8192] (2 MB)
    float* kws = out + (size_t)DIMC * LSEQ;      // k[768][8192] (25 MB)

    hipLaunchKernelGGL(hidden_kernel, dim3(LSEQ / 4), dim3(256), 0, stream,
                       W0, b0, W1, b1, W2, b2, freq, hws);
    hipLaunchKernelGGL(filter_kernel, dim3(LSEQ / 256, DIMC / DCHUNK), dim3(256), 0, stream,
                       hws, Wf, kws);
    hipLaunchKernelGGL(conv_kernel, dim3(DIMC), dim3(1024), 0, stream,
                       x, kws, bias, out);
}